// Round 5
// baseline (14667.833 us; speedup 1.0000x reference)
//
#include <hip/hip_runtime.h>
#include <hip/hip_bf16.h>

#define VOCAB 32000
#define HID 512
#define BATCH 256
#define SEQ 128
#define NL 5
#define BH (BATCH*HID)      // 131072
#define G4H (4*HID)         // 2048
#define NBLK 160            // 5 layers x 32 column-slices, 1 block/CU
#define HDEPTH 4            // h rotation depth

typedef __attribute__((ext_vector_type(8))) short short8;
typedef __attribute__((ext_vector_type(4))) float float4v;
typedef unsigned long long u64;

__device__ __forceinline__ float sigmoid_f(float x) {
    return 1.f / (1.f + __expf(-x));
}
__device__ __forceinline__ float tanh_f(float x) {
    float ax = fabsf(x);
    float e = __expf(2.f * ax);
    float t = 1.f - 2.f / (e + 1.f);
    return copysignf(t, x);
}
__device__ __forceinline__ short bf16bits(float f) {
    union { __hip_bfloat16 b; short s; } u;
    u.b = __float2bfloat16(f);
    return u.s;
}
__device__ __forceinline__ short8 load8f(const float* p) {   // fp32 -> bf16 frag
    float4v lo = *(const float4v*)p;
    float4v hi = *(const float4v*)(p + 4);
    short8 r;
    r[0] = bf16bits(lo[0]); r[1] = bf16bits(lo[1]);
    r[2] = bf16bits(lo[2]); r[3] = bf16bits(lo[3]);
    r[4] = bf16bits(hi[0]); r[5] = bf16bits(hi[1]);
    r[6] = bf16bits(hi[2]); r[7] = bf16bits(hi[3]);
    return r;
}
__device__ __forceinline__ short8 load8b(const __hip_bfloat16* p) {
    return *(const short8*)p;
}
// coherent (agent-scope, LLC-direct) 16B fragment load as two u64 atomics
__device__ __forceinline__ short8 load8coh(const __hip_bfloat16* p) {
    union { u64 q[2]; short8 s; } u;
    u.q[0] = __hip_atomic_load((const u64*)p, __ATOMIC_RELAXED, __HIP_MEMORY_SCOPE_AGENT);
    u.q[1] = __hip_atomic_load((const u64*)(p + 4), __ATOMIC_RELAXED, __HIP_MEMORY_SCOPE_AGENT);
    return u.s;
}

// h layout: slice-contiguous [d(4)][l][j(32)][m(256)][c(16)] bf16
__device__ __forceinline__ size_t hidx(int d, int l, int j, int m, int c) {
    return ((((size_t)d * NL + l) * 32 + j) * 256 + m) * 16 + c;
}

// ---------------------------------------------------------------------------
// init: h0 fp32 -> slot-3 bf16 h buffer (slice layout); zero done counters
// done layout: done[(l*16 + waveid)*4], 320 ints
// ---------------------------------------------------------------------------
__global__ void init_state_k(const float* __restrict__ h0,
                             __hip_bfloat16* __restrict__ hbuf,
                             int* __restrict__ done) {
    int i = blockIdx.x * 256 + threadIdx.x;   // grid covers NL*BH exactly
    int l = i / BH, r = i % BH;
    int m = r >> 9, col = r & 511;
    hbuf[hidx(HDEPTH - 1, l, col >> 4, m, col & 15)] = __float2bfloat16(h0[i]);
    if (blockIdx.x == 0) {
        done[threadIdx.x] = 0;
        if (threadIdx.x < 64) done[256 + threadIdx.x] = 0;
    }
}

// ---------------------------------------------------------------------------
// persistent wavefront LSTM — wave-autonomous (NO in-loop __syncthreads).
// block = (layer l, 16-col slice j); 16 waves, wave w owns rows [16w,16w+16).
// Weights bf16 in LDS (128 KB, frag order). c in registers.
// h: 4-deep rotation, relaxed agent-scope atomics (LLC-direct, fence-free).
// Flags: per-(layer,waveid) monotonic counters; lane-parallel polling;
// per-wave release increments (vmcnt drain is wave-local).
// ---------------------------------------------------------------------------
__global__ __launch_bounds__(1024) void lstm_persist_k(
    const int* __restrict__ x,
    const float* __restrict__ emb,
    const float* __restrict__ W_ih,
    const float* __restrict__ W_hh,
    const float* __restrict__ b_ih,
    const float* __restrict__ b_hh,
    const float* __restrict__ c0,
    __hip_bfloat16* __restrict__ hbuf,
    int* __restrict__ done)
{
    __shared__ short lw[65536];               // 128 KB weight slice
    __shared__ short tsc[16 * 256];           // 8 KB per-wave transpose scratch

    const int tid = threadIdx.x;
    const int xcd = blockIdx.x & 7;
    const int ixc = blockIdx.x >> 3;
    const int slot = xcd * 20 + ixc;          // XCD-contiguous slots
    const int l = slot >> 5;                  // layer 0..4
    const int j = slot & 31;                  // col slice 0..31
    const int jbase = j << 4;

    const int wave = tid >> 6, lane = tid & 63;
    const int quad = lane >> 4, l16 = lane & 15;
    const int m16 = wave << 4;

    const float* Wg[2] = { W_ih + (size_t)l * G4H * HID,
                           W_hh + (size_t)l * G4H * HID };

    // ---- stage weight slice into LDS in fragment order ----
    for (int e = tid; e < 8192; e += 1024) {
        int row = e >> 6;
        int kc  = (e & 63) << 3;
        int gemm = row >> 6, r2 = row & 63, g = r2 >> 4, rl = r2 & 15;
        const float* src = Wg[gemm] + (size_t)(g * HID + jbase + rl) * HID + kc;
        short8 v = load8f(src);
        int kt = kc >> 5, q = (kc >> 3) & 3;
        int fragslot = ((gemm * 4 + g) * 16 + kt) * 64 + (q * 16 + rl);
        *(short8*)&lw[(size_t)fragslot * 8] = v;
    }

    // ---- per-lane persistent state ----
    const int jj = jbase + l16;
    float bias[4], c_r[4];
#pragma unroll
    for (int g = 0; g < 4; ++g)
        bias[g] = b_ih[l * G4H + g * HID + jj] + b_hh[l * G4H + g * HID + jj];
#pragma unroll
    for (int r = 0; r < 4; ++r)
        c_r[r] = c0[(size_t)l * BH + (size_t)(m16 + quad * 4 + r) * HID + jj];

    const short* lwb = lw + (size_t)lane * 8;
    const size_t aoff = (size_t)(m16 + l16) * 16 + (size_t)(quad & 1) * 8;
    const int shi = quad >> 1;

    // ---- lane-parallel poll setup (3 groups of 16 lanes) ----
    const int grp = lane >> 4;                // 0: l-1, 1: self, 2: l+1, 3: idle
    const int wsel = l16;
    int lsel = (grp == 0) ? (l - 1) : (grp == 1) ? l : (l + 1);
    int lc = lsel < 0 ? 0 : (lsel > NL - 1 ? NL - 1 : lsel);
    const int* pollp = &done[(lc * 16 + wsel) * 4];
    const bool gvalid0 = (grp == 0) && (l > 0);
    const bool gvalid1 = (grp == 1);
    const bool gvalid2 = (grp == 2) && (l < NL - 1);

    __syncthreads();                          // LDS weights ready (only barrier)

    for (int t = 0; t < SEQ; ++t) {
        // ---- dependency wait: all lanes poll in parallel, one ballot/round ----
        {
            int need = gvalid0 ? 32 * (t + 1)
                     : gvalid1 ? 32 * t
                     : gvalid2 ? 32 * (t - 3) : 0;
            bool valid = (gvalid0) || (gvalid1 && t > 0) || (gvalid2 && t >= 4);
            while (true) {
                int v = __hip_atomic_load(pollp, __ATOMIC_RELAXED,
                                          __HIP_MEMORY_SCOPE_AGENT);
                bool ok = !valid || (v >= need);
                if (__ballot(ok) == ~0ull) break;
                __builtin_amdgcn_s_sleep(1);
            }
        }

        const int dcur = t & (HDEPTH - 1);
        const int dprev = (t - 1) & (HDEPTH - 1);     // t=0 -> 3 (h0)
        const __hip_bfloat16* hpr_b = hbuf + hidx(dprev, l, 0, 0, 0) + aoff;

        float4v acc[4];
#pragma unroll
        for (int g = 0; g < 4; ++g) acc[g] = (float4v){0.f, 0.f, 0.f, 0.f};

        if (l == 0) {
            int tok = x[t * BATCH + m16 + l16];
            const float* ar = emb + (size_t)tok * HID;
            short8 ah[3];
#pragma unroll
            for (int pf = 0; pf < 3; ++pf)
                ah[pf] = load8coh(hpr_b + (size_t)(2 * pf + shi) * 4096);
#pragma unroll
            for (int kt = 0; kt < 16; ++kt) {
                short8 a_in = load8f(ar + kt * 32 + quad * 8);
                short8 a_h = ah[kt % 3];
                if (kt + 3 < 16)
                    ah[kt % 3] = load8coh(hpr_b + (size_t)(2 * (kt + 3) + shi) * 4096);
#pragma unroll
                for (int g = 0; g < 4; ++g) {
                    short8 b0 = *(const short8*)(lwb + (size_t)(g * 16 + kt) * 512);
                    short8 b1 = *(const short8*)(lwb + (size_t)((4 + g) * 16 + kt) * 512);
                    acc[g] = __builtin_amdgcn_mfma_f32_16x16x32_bf16(a_in, b0, acc[g], 0, 0, 0);
                    acc[g] = __builtin_amdgcn_mfma_f32_16x16x32_bf16(a_h,  b1, acc[g], 0, 0, 0);
                }
            }
        } else {
            const __hip_bfloat16* hin_b = hbuf + hidx(dcur, l - 1, 0, 0, 0) + aoff;
            short8 ai[3], ah[3];
#pragma unroll
            for (int pf = 0; pf < 3; ++pf) {
                ai[pf] = load8coh(hin_b + (size_t)(2 * pf + shi) * 4096);
                ah[pf] = load8coh(hpr_b + (size_t)(2 * pf + shi) * 4096);
            }
#pragma unroll
            for (int kt = 0; kt < 16; ++kt) {
                short8 a_in = ai[kt % 3];
                short8 a_h  = ah[kt % 3];
                if (kt + 3 < 16) {
                    ai[kt % 3] = load8coh(hin_b + (size_t)(2 * (kt + 3) + shi) * 4096);
                    ah[kt % 3] = load8coh(hpr_b + (size_t)(2 * (kt + 3) + shi) * 4096);
                }
#pragma unroll
                for (int g = 0; g < 4; ++g) {
                    short8 b0 = *(const short8*)(lwb + (size_t)(g * 16 + kt) * 512);
                    short8 b1 = *(const short8*)(lwb + (size_t)((4 + g) * 16 + kt) * 512);
                    acc[g] = __builtin_amdgcn_mfma_f32_16x16x32_bf16(a_in, b0, acc[g], 0, 0, 0);
                    acc[g] = __builtin_amdgcn_mfma_f32_16x16x32_bf16(a_h,  b1, acc[g], 0, 0, 0);
                }
            }
        }

        // ---- epilogue: register c; transpose 16x16 tile via wave-local LDS;
        //      coalesced 8B agent stores (512B contiguous per wave) ----
        short* ts = &tsc[wave * 256];
#pragma unroll
        for (int r = 0; r < 4; ++r) {
            float iv = sigmoid_f(acc[0][r] + bias[0]);
            float fv = sigmoid_f(acc[1][r] + bias[1]);
            float gv = tanh_f(acc[2][r] + bias[2]);
            float ov = sigmoid_f(acc[3][r] + bias[3]);
            c_r[r] = fv * c_r[r] + iv * gv;
            ts[(quad * 4 + r) * 16 + l16] = bf16bits(ov * tanh_f(c_r[r]));
        }
        {
            int row = lane >> 2, cp4 = lane & 3;
            u64 v = *(const u64*)&ts[row * 16 + cp4 * 4];   // lgkmcnt auto-waits
            u64* dst = (u64*)(hbuf + hidx(dcur, l, j, m16 + row, cp4 * 4));
            __hip_atomic_store(dst, v, __ATOMIC_RELAXED, __HIP_MEMORY_SCOPE_AGENT);
        }

        // per-wave release increment (drains this wave's stores only)
        if (lane == 0)
            __hip_atomic_fetch_add(&done[(l * 16 + wave) * 4], 1,
                                   __ATOMIC_RELEASE, __HIP_MEMORY_SCOPE_AGENT);
    }
}

// ---------------------------------------------------------------------------
// output projection: out(256 x 32000) = h_final @ W_out^T + b_out
// ---------------------------------------------------------------------------
__global__ __launch_bounds__(512) void out_gemm_k(
    const __hip_bfloat16* __restrict__ hbuf,
    const float* __restrict__ W_out,
    const float* __restrict__ b_out,
    float* __restrict__ out)
{
    const int nb = blockIdx.x;
    const int tid = threadIdx.x;
    const int wave = tid >> 6, lane = tid & 63;
    const int quad = lane >> 4, l16 = lane & 15;
    const int nt = wave & 3, mh = wave >> 2;

    const __hip_bfloat16* hfin = hbuf + hidx((SEQ - 1) & (HDEPTH - 1), NL - 1, 0, 0, 0);
    const int shi = quad >> 1;
    const size_t coff = (size_t)(quad & 1) * 8;

    const int ncol = nb * 64 + nt * 16 + l16;
    const float* brow = W_out + (size_t)ncol * HID;

    float4v acc[8];
#pragma unroll
    for (int mt = 0; mt < 8; ++mt) acc[mt] = (float4v){0.f, 0.f, 0.f, 0.f};

#pragma unroll 2
    for (int kt = 0; kt < 16; ++kt) {
        short8 b = load8f(brow + kt * 32 + quad * 8);
        const __hip_bfloat16* abase =
            hfin + (size_t)(2 * kt + shi) * 4096 + coff;
#pragma unroll
        for (int mt = 0; mt < 8; ++mt) {
            short8 a = load8b(abase + (size_t)(mh * 128 + mt * 16 + l16) * 16);
            acc[mt] = __builtin_amdgcn_mfma_f32_16x16x32_bf16(a, b, acc[mt], 0, 0, 0);
        }
    }

    float bo = b_out[ncol];
#pragma unroll
    for (int mt = 0; mt < 8; ++mt) {
#pragma unroll
        for (int r = 0; r < 4; ++r) {
            int m = mh * 128 + mt * 16 + quad * 4 + r;
            out[(size_t)m * VOCAB + ncol] = acc[mt][r] + bo;
        }
    }
}

extern "C" void kernel_launch(void* const* d_in, const int* in_sizes, int n_in,
                              void* d_out, int out_size, void* d_ws, size_t ws_size,
                              hipStream_t stream) {
    const int* x        = (const int*)d_in[0];
    const float* h0     = (const float*)d_in[1];
    const float* c0     = (const float*)d_in[2];
    const float* emb    = (const float*)d_in[3];
    const float* W_ih   = (const float*)d_in[4];
    const float* W_hh   = (const float*)d_in[5];
    const float* b_ih   = (const float*)d_in[6];
    const float* b_hh   = (const float*)d_in[7];
    const float* W_out  = (const float*)d_in[8];
    const float* b_out  = (const float*)d_in[9];
    float* out          = (float*)d_out;

    // ws: h 4-deep rotation (4,NL,B,H) bf16 slice layout | done counters (320 ints)
    __hip_bfloat16* hbuf = (__hip_bfloat16*)d_ws;
    int* done = (int*)((char*)d_ws + (size_t)HDEPTH * NL * BH * sizeof(__hip_bfloat16));

    init_state_k<<<(NL * BH) / 256, 256, 0, stream>>>(h0, hbuf, done);

    lstm_persist_k<<<NBLK, 1024, 0, stream>>>(x, emb, W_ih, W_hh, b_ih, b_hh,
                                              c0, hbuf, done);

    out_gemm_k<<<VOCAB / 64, 512, 0, stream>>>(hbuf, W_out, b_out, out);
}